// Round 1
// baseline (389.610 us; speedup 1.0000x reference)
//
#include <hip/hip_runtime.h>
#include <hip/hip_bf16.h>

typedef __bf16 bf16;
typedef __bf16 bf16x4 __attribute__((ext_vector_type(4)));
typedef __bf16 bf16x8 __attribute__((ext_vector_type(8)));
typedef float f32x4 __attribute__((ext_vector_type(4)));

#define MFMA16(A, B, C) __builtin_amdgcn_mfma_f32_16x16x32_bf16((A), (B), (C), 0, 0, 0)

__device__ __forceinline__ void gload_lds16(const void* g, void* l) {
  __builtin_amdgcn_global_load_lds(
      (const __attribute__((address_space(1))) void*)g,
      (__attribute__((address_space(3))) void*)l, 16, 0, 0);
}

// ---------------- elementwise casts ----------------
__global__ void cast_f32_bf16_k(const float* __restrict__ src, bf16* __restrict__ dst, int n4) {
  int i = blockIdx.x * blockDim.x + threadIdx.x;
  if (i >= n4) return;
  float4 v = ((const float4*)src)[i];
  bf16x4 o = {(bf16)v.x, (bf16)v.y, (bf16)v.z, (bf16)v.w};
  ((bf16x4*)dst)[i] = o;
}

// ---------------- RoPE table ----------------
__global__ void rope_table_k(float* __restrict__ cosT, float* __restrict__ sinT) {
  int tid = blockIdx.x * blockDim.x + threadIdx.x;  // S*64
  int s = tid >> 6, i = tid & 63;
  float inv = powf(1.0e6f, -(float)i / 64.0f);
  float ang = (float)s * inv;
  cosT[tid] = cosf(ang);
  sinT[tid] = sinf(ang);
}

// ---------------- RoPE apply + reshape ----------------
// Qlin [B*S, 2048] -> Qr [B,H,S,128] with rotate-half RoPE
__global__ void rope_q_k(const bf16* __restrict__ Qlin, const float* __restrict__ cosT,
                         const float* __restrict__ sinT, bf16* __restrict__ Qr) {
  int tid = blockIdx.x * blockDim.x + threadIdx.x;  // B*S*H*64 = 4194304
  int i = tid & 63;
  int h = (tid >> 6) & 15;
  int s = (tid >> 10) & 2047;
  int b = tid >> 21;
  const bf16* src = Qlin + ((size_t)(b * 2048 + s)) * 2048 + h * 128;
  float x1 = (float)src[i], x2 = (float)src[i + 64];
  float c = cosT[s * 64 + i], sn = sinT[s * 64 + i];
  bf16* dst = Qr + ((size_t)((b * 16 + h) * 2048 + s)) * 128;
  dst[i] = (bf16)(x1 * c - x2 * sn);
  dst[i + 64] = (bf16)(x2 * c + x1 * sn);
}

// KVlin [B*S, 512] (k = cols [0,256)) -> Kr [B,KVH,S,128] with RoPE
__global__ void rope_k_k(const bf16* __restrict__ KVlin, const float* __restrict__ cosT,
                         const float* __restrict__ sinT, bf16* __restrict__ Kr) {
  int tid = blockIdx.x * blockDim.x + threadIdx.x;  // B*S*KVH*64 = 524288
  int i = tid & 63;
  int kvh = (tid >> 6) & 1;
  int s = (tid >> 7) & 2047;
  int b = tid >> 18;
  const bf16* src = KVlin + ((size_t)(b * 2048 + s)) * 512 + kvh * 128;
  float x1 = (float)src[i], x2 = (float)src[i + 64];
  float c = cosT[s * 64 + i], sn = sinT[s * 64 + i];
  bf16* dst = Kr + ((size_t)((b * 2 + kvh) * 2048 + s)) * 128;
  dst[i] = (bf16)(x1 * c - x2 * sn);
  dst[i + 64] = (bf16)(x2 * c + x1 * sn);
}

// KVlin v-part (cols [256,512)) -> Vt [B,KVH,128,S] (transposed for PV B-operand)
__global__ void v_tr_k(const bf16* __restrict__ KVlin, bf16* __restrict__ Vt) {
  int tid = blockIdx.x * blockDim.x + threadIdx.x;  // B*KVH*128*S = 1048576
  int s = tid & 2047;
  int d = (tid >> 11) & 127;
  int kvh = (tid >> 18) & 1;
  int b = tid >> 19;
  Vt[tid] = KVlin[((size_t)(b * 2048 + s)) * 512 + 256 + kvh * 128 + d];
}

// ---------------- BT GEMM: C[M,N] = A[M,K] * B[N,K]^T (+bias), bf16 in, fp32 acc ----------------
template <typename OutT>
__global__ __launch_bounds__(256) void gemm_bt_k(
    const bf16* __restrict__ A, const bf16* __restrict__ Bm,
    const float* __restrict__ bias, OutT* __restrict__ C, int M, int N, int K) {
  __shared__ __align__(16) bf16 As[128 * 64];
  __shared__ __align__(16) bf16 Bs[128 * 64];
  const int tid = threadIdx.x;
  const int lane = tid & 63;
  const int w = tid >> 6;
  const int wr = w >> 1, wc = w & 1;
  const size_t bm = (size_t)blockIdx.y * 128;
  const size_t bn = (size_t)blockIdx.x * 128;
  const int l8r = lane >> 3, l8c = lane & 7;

  f32x4 acc[4][4] = {};

  for (int k0 = 0; k0 < K; k0 += 64) {
#pragma unroll
    for (int i = 0; i < 4; ++i) {
      int c = w * 4 + i;
      int row = c * 8 + l8r;
      gload_lds16(A + (bm + row) * (size_t)K + k0 + l8c * 8, (char*)As + c * 1024);
      gload_lds16(Bm + (bn + row) * (size_t)K + k0 + l8c * 8, (char*)Bs + c * 1024);
    }
    __syncthreads();
#pragma unroll
    for (int kk = 0; kk < 2; ++kk) {
      bf16x8 af[4], bfr[4];
#pragma unroll
      for (int mi = 0; mi < 4; ++mi) {
        int r = wr * 64 + mi * 16 + (lane & 15);
        af[mi] = *(const bf16x8*)(As + r * 64 + kk * 32 + (lane >> 4) * 8);
      }
#pragma unroll
      for (int ni = 0; ni < 4; ++ni) {
        int r = wc * 64 + ni * 16 + (lane & 15);
        bfr[ni] = *(const bf16x8*)(Bs + r * 64 + kk * 32 + (lane >> 4) * 8);
      }
#pragma unroll
      for (int mi = 0; mi < 4; ++mi)
#pragma unroll
        for (int ni = 0; ni < 4; ++ni)
          acc[mi][ni] = MFMA16(af[mi], bfr[ni], acc[mi][ni]);
    }
    __syncthreads();
  }
#pragma unroll
  for (int mi = 0; mi < 4; ++mi) {
#pragma unroll
    for (int ni = 0; ni < 4; ++ni) {
      int col = (int)bn + wc * 64 + ni * 16 + (lane & 15);
      float bv = bias ? bias[col] : 0.0f;
#pragma unroll
      for (int j = 0; j < 4; ++j) {
        size_t row = bm + wr * 64 + mi * 16 + (lane >> 4) * 4 + j;
        C[row * N + col] = (OutT)(acc[mi][ni][j] + bv);
      }
    }
  }
}

// ---------------- Flash attention (causal, GQA 8:1) ----------------
// Qr [B,H,S,128], Kr [B,KVH,S,128], Vt [B,KVH,128,S] -> O [B,S,H*128] (bf16)
// grid (16, B*H); block 256 = 4 waves x 16 q-rows; q-tile pair (qt, 31-qt) for balance.
__global__ __launch_bounds__(256, 2) void attn_k(
    const bf16* __restrict__ Qr, const bf16* __restrict__ Kr, const bf16* __restrict__ Vt,
    bf16* __restrict__ O) {
  __shared__ __align__(16) bf16 Ks[64 * 128];   // [kv][hd], XOR-swizzled cols
  __shared__ __align__(16) bf16 Vs[128 * 64];   // [hd][kv], XOR-swizzled cols
  __shared__ __align__(16) bf16 Ps[4][16][72];  // per-wave P, +8 pad

  const int S = 2048;
  const int lane = threadIdx.x & 63;
  const int w = threadIdx.x >> 6;
  const int bh = blockIdx.y;
  const int b = bh >> 4, h = bh & 15;
  const int kvh = h >> 3;
  const bf16* Qbase = Qr + (size_t)bh * S * 128;
  const bf16* Kbase = Kr + (size_t)(b * 2 + kvh) * S * 128;
  const bf16* Vbase = Vt + (size_t)(b * 2 + kvh) * 128 * S;
  const float scale = 0.08838834764831845f;  // 1/sqrt(128)

  for (int half = 0; half < 2; ++half) {
    const int qt = half ? (31 - blockIdx.x) : blockIdx.x;
    const int q0 = qt * 64;
    const int qrow = q0 + w * 16 + (lane & 15);
    bf16x8 qf[4];
#pragma unroll
    for (int kk = 0; kk < 4; ++kk)
      qf[kk] = *(const bf16x8*)(Qbase + (size_t)qrow * 128 + kk * 32 + (lane >> 4) * 8);

    float m_run[4], l_run[4];
    f32x4 o_acc[8] = {};
#pragma unroll
    for (int j = 0; j < 4; ++j) { m_run[j] = -3.0e38f; l_run[j] = 0.0f; }

    for (int t = 0; t <= qt; ++t) {
      // stage K tile [64][128] and V^T tile [128][64]; pre-swizzled global source,
      // linear LDS dest (global_load_lds writes base + lane*16)
#pragma unroll
      for (int i = 0; i < 4; ++i) {
        int c = w * 4 + i;
        {
          int row = c * 4 + (lane >> 4);
          int sc = ((lane & 15) ^ (row & 7)) * 8;
          gload_lds16(Kbase + (size_t)(t * 64 + row) * 128 + sc, (char*)Ks + c * 1024);
        }
        {
          int row = c * 8 + (lane >> 3);
          int sc = ((lane & 7) ^ (row & 7)) * 8;
          gload_lds16(Vbase + (size_t)row * S + t * 64 + sc, (char*)Vs + c * 1024);
        }
      }
      __syncthreads();

      // QK^T: S[q][kv], q = lane&15 rows of this wave, kv cols = ni*16 + lane&15
      f32x4 sacc[4] = {};
#pragma unroll
      for (int kk = 0; kk < 4; ++kk) {
#pragma unroll
        for (int ni = 0; ni < 4; ++ni) {
          int n = ni * 16 + (lane & 15);
          int off = n * 256 + ((kk * 64 + (lane >> 4) * 16) ^ ((n & 7) << 4));
          bf16x8 kf = *(const bf16x8*)((const char*)Ks + off);
          sacc[ni] = MFMA16(qf[kk], kf, sacc[ni]);
        }
      }

      // scale + causal mask + online softmax (rows: (lane>>4)*4 + j)
      float tmax[4] = {-3.0e38f, -3.0e38f, -3.0e38f, -3.0e38f};
      int qrb = q0 + w * 16 + (lane >> 4) * 4;
#pragma unroll
      for (int ni = 0; ni < 4; ++ni) {
        int kc = t * 64 + ni * 16 + (lane & 15);
#pragma unroll
        for (int j = 0; j < 4; ++j) {
          float s = sacc[ni][j] * scale;
          if (kc > qrb + j) s = -3.0e38f;
          sacc[ni][j] = s;
          tmax[j] = fmaxf(tmax[j], s);
        }
      }
#pragma unroll
      for (int j = 0; j < 4; ++j) {
#pragma unroll
        for (int d = 1; d < 16; d <<= 1) tmax[j] = fmaxf(tmax[j], __shfl_xor(tmax[j], d, 64));
        float mnew = fmaxf(m_run[j], tmax[j]);
        float corr = __expf(m_run[j] - mnew);
        m_run[j] = mnew;
        l_run[j] *= corr;
#pragma unroll
        for (int n2 = 0; n2 < 8; ++n2) o_acc[n2][j] *= corr;
      }
      float tsum[4] = {0.f, 0.f, 0.f, 0.f};
#pragma unroll
      for (int ni = 0; ni < 4; ++ni) {
#pragma unroll
        for (int j = 0; j < 4; ++j) {
          float p = __expf(sacc[ni][j] - m_run[j]);
          tsum[j] += p;
          Ps[w][(lane >> 4) * 4 + j][ni * 16 + (lane & 15)] = (bf16)p;
        }
      }
#pragma unroll
      for (int j = 0; j < 4; ++j) {
#pragma unroll
        for (int d = 1; d < 16; d <<= 1) tsum[j] += __shfl_xor(tsum[j], d, 64);
        l_run[j] += tsum[j];
      }

      // PV: O[q][hd] += P[q][kv] * V[kv][hd]; B-frag = contiguous row of V^T
#pragma unroll
      for (int ks = 0; ks < 2; ++ks) {
        const bf16* pp = &Ps[w][lane & 15][ks * 32 + (lane >> 4) * 8];
        bf16x4 plo = *(const bf16x4*)pp;
        bf16x4 phi = *(const bf16x4*)(pp + 4);
        bf16x8 pf = __builtin_shufflevector(plo, phi, 0, 1, 2, 3, 4, 5, 6, 7);
#pragma unroll
        for (int n2 = 0; n2 < 8; ++n2) {
          int n = n2 * 16 + (lane & 15);
          int off = n * 128 + ((ks * 64 + (lane >> 4) * 16) ^ ((n & 7) << 4));
          bf16x8 vf = *(const bf16x8*)((const char*)Vs + off);
          o_acc[n2] = MFMA16(pf, vf, o_acc[n2]);
        }
      }
      __syncthreads();
    }

    // epilogue: O[b, qr, h*128 + col]
#pragma unroll
    for (int n2 = 0; n2 < 8; ++n2) {
#pragma unroll
      for (int j = 0; j < 4; ++j) {
        int qr = q0 + w * 16 + (lane >> 4) * 4 + j;
        O[((size_t)(b * S + qr)) * 2048 + h * 128 + n2 * 16 + (lane & 15)] =
            (bf16)(o_acc[n2][j] / l_run[j]);
      }
    }
  }
}

// ---------------- launch ----------------
extern "C" void kernel_launch(void* const* d_in, const int* in_sizes, int n_in,
                              void* d_out, int out_size, void* d_ws, size_t ws_size,
                              hipStream_t stream) {
  const float* x   = (const float*)d_in[0];
  // d_in[1] = attn_mask (pure causal; applied analytically in attn_k)
  const float* Wq  = (const float*)d_in[2];
  const float* bq  = (const float*)d_in[3];
  const float* Wkv = (const float*)d_in[4];
  const float* bkv = (const float*)d_in[5];
  const float* Wo  = (const float*)d_in[6];
  float* out = (float*)d_out;
  char* ws = (char*)d_ws;

  bf16* xb    = (bf16*)(ws + 0);          // 16,777,216 B
  bf16* Wqb   = (bf16*)(ws + 16777216);   //  8,388,608
  bf16* Wkvb  = (bf16*)(ws + 25165824);   //  2,097,152
  bf16* Wob   = (bf16*)(ws + 27262976);   //  8,388,608
  bf16* Qlin  = (bf16*)(ws + 35651584);   // 16,777,216
  bf16* KVlin = (bf16*)(ws + 52428800);   //  4,194,304
  bf16* Qrr   = (bf16*)(ws + 56623104);   // 16,777,216
  bf16* Krr   = (bf16*)(ws + 73400320);   //  2,097,152
  bf16* Vtt   = (bf16*)(ws + 75497472);   //  2,097,152
  bf16* Oat   = (bf16*)(ws + 77594624);   // 16,777,216
  float* cosT = (float*)(ws + 94371840);  //    524,288
  float* sinT = (float*)(ws + 94896128);  //    524,288  (total ~91 MB)

  cast_f32_bf16_k<<<8192, 256, 0, stream>>>(x, xb, 2097152);
  cast_f32_bf16_k<<<4096, 256, 0, stream>>>(Wq, Wqb, 1048576);
  cast_f32_bf16_k<<<1024, 256, 0, stream>>>(Wkv, Wkvb, 262144);
  cast_f32_bf16_k<<<4096, 256, 0, stream>>>(Wo, Wob, 1048576);
  rope_table_k<<<512, 256, 0, stream>>>(cosT, sinT);

  gemm_bt_k<bf16><<<dim3(16, 32), 256, 0, stream>>>(xb, Wqb, bq, Qlin, 4096, 2048, 2048);
  gemm_bt_k<bf16><<<dim3(4, 32), 256, 0, stream>>>(xb, Wkvb, bkv, KVlin, 4096, 512, 2048);

  rope_q_k<<<16384, 256, 0, stream>>>(Qlin, cosT, sinT, Qrr);
  rope_k_k<<<2048, 256, 0, stream>>>(KVlin, cosT, sinT, Krr);
  v_tr_k<<<4096, 256, 0, stream>>>(KVlin, Vtt);

  attn_k<<<dim3(16, 32), 256, 0, stream>>>(Qrr, Krr, Vtt, Oat);

  gemm_bt_k<float><<<dim3(16, 32), 256, 0, stream>>>(Oat, Wob, nullptr, out, 4096, 2048, 2048);
}